// Round 1
// baseline (245.946 us; speedup 1.0000x reference)
//
#include <hip/hip_runtime.h>
#include <math.h>

#define DD 192
#define HH 192
#define WW 192
#define NVOX (DD*HH*WW)        // 7077888
#define NV4  (NVOX/4)          // 1769472
#define RB   1024              // reduction blocks
#define RT   256               // reduction threads per block

typedef float f4 __attribute__((ext_vector_type(4)));

struct Consts {
    float tx, ty, tz;          // grid translation
    float wgt[8];              // corner weights, index = dz*4+dy*2+dx
    int   dx0, dy0, dz0;       // integer corner offsets (floor of shift)
};

__device__ __forceinline__ float gcoord(int i, int n) {
    return -1.0f + (float)i * (2.0f / (float)(n - 1));
}

// ws layout: [0..63] gsum (8 doubles), [64..67] counter, [128..] Consts
// quantities: 0:sum_x 1:sum x*gx 2:sum x*gy 3:sum x*gz  4..7: same for y
__global__ void reduce_kernel(const float* __restrict__ x,
                              const float* __restrict__ y,
                              double* __restrict__ gsum,
                              unsigned int* __restrict__ counter,
                              Consts* __restrict__ cs) {
    double acc[8] = {0,0,0,0,0,0,0,0};
    int tid = blockIdx.x * blockDim.x + threadIdx.x;
    const float4* x4 = (const float4*)x;
    const float4* y4 = (const float4*)y;
    for (int i = tid; i < NV4; i += RB * RT) {
        float4 xv = x4[i];
        float4 yv = y4[i];
        int base = i * 4;
        int w = base % WW;          // multiple of 4
        int rem = base / WW;
        int h = rem % HH;
        int d = rem / HH;
        float gy = gcoord(h, HH);
        float gz = gcoord(d, DD);
        float xs[4] = {xv.x, xv.y, xv.z, xv.w};
        float ys[4] = {yv.x, yv.y, yv.z, yv.w};
        // group-sum in fp32 (4 values, error ~1ulp), widen once
        float sx = 0.f, sy = 0.f, sxg = 0.f, syg = 0.f;
        #pragma unroll
        for (int k = 0; k < 4; ++k) {
            float gx = gcoord(w + k, WW);
            sx += xs[k]; sxg = fmaf(xs[k], gx, sxg);
            sy += ys[k]; syg = fmaf(ys[k], gx, syg);
        }
        acc[0] += (double)sx;
        acc[1] += (double)sxg;
        acc[2] += (double)(sx * gy);
        acc[3] += (double)(sx * gz);
        acc[4] += (double)sy;
        acc[5] += (double)syg;
        acc[6] += (double)(sy * gy);
        acc[7] += (double)(sy * gz);
    }
    #pragma unroll
    for (int q = 0; q < 8; ++q) {
        double v = acc[q];
        #pragma unroll
        for (int off = 32; off > 0; off >>= 1)
            v += __shfl_down(v, off, 64);
        acc[q] = v;
    }
    __shared__ double lds[4][8];
    int lane = threadIdx.x & 63;
    int wave = threadIdx.x >> 6;
    if (lane == 0) {
        #pragma unroll
        for (int q = 0; q < 8; ++q) lds[wave][q] = acc[q];
    }
    __syncthreads();
    // block sums -> device-scope f64 atomics (coherent across XCDs)
    if (threadIdx.x < 8) {
        int q = threadIdx.x;
        atomicAdd(&gsum[q], lds[0][q] + lds[1][q] + lds[2][q] + lds[3][q]);
    }
    __threadfence();               // gsum adds visible before counter bump
    if (threadIdx.x == 0) {
        unsigned int old = atomicAdd(counter, 1u);
        if (old == RB - 1) {       // last block: finalize inline
            __threadfence();
            double s[8];
            #pragma unroll
            for (int q = 0; q < 8; ++q)
                s[q] = atomicAdd(&gsum[q], 0.0);   // coherent read
            double tx = s[1]/s[0] - s[5]/s[4];
            double ty = s[2]/s[0] - s[6]/s[4];
            double tz = s[3]/s[0] - s[7]/s[4];
            cs->tx = (float)tx; cs->ty = (float)ty; cs->tz = (float)tz;
            double cx = tx * (double)(WW - 1) * 0.5;
            double cy = ty * (double)(HH - 1) * 0.5;
            double cz = tz * (double)(DD - 1) * 0.5;
            double fx = floor(cx), fy = floor(cy), fz = floor(cz);
            float wx = (float)(cx - fx), wy = (float)(cy - fy), wz = (float)(cz - fz);
            cs->dx0 = (int)fx; cs->dy0 = (int)fy; cs->dz0 = (int)fz;
            #pragma unroll
            for (int k = 0; k < 8; ++k) {
                float wzz = (k & 4) ? wz : 1.0f - wz;
                float wyy = (k & 2) ? wy : 1.0f - wy;
                float wxx = (k & 1) ? wx : 1.0f - wx;
                cs->wgt[k] = wzz * wyy * wxx;
            }
        }
    }
}

// Fused: grid write (direct float4) + constant-shift trilinear, 4 voxels/thread.
__global__ void __launch_bounds__(256) main_kernel(const float* __restrict__ x,
                                                   const Consts* __restrict__ csp,
                                                   f4* __restrict__ out_t4,
                                                   f4* __restrict__ out_g4) {
    const Consts c = *csp;              // uniform -> scalar loads
    int idx = blockIdx.x * 256 + threadIdx.x;   // quad index, 0..NV4-1
    int wq  = idx % (WW / 4);
    int rem = idx / (WW / 4);
    int h = rem % HH;
    int d = rem / HH;
    int w = wq * 4;

    // ---- grid output: 12 floats = 3 float4 per thread, direct stores
    float gy  = gcoord(h, HH) + c.ty;
    float gz  = gcoord(d, DD) + c.tz;
    float gx0 = gcoord(w + 0, WW) + c.tx;
    float gx1 = gcoord(w + 1, WW) + c.tx;
    float gx2 = gcoord(w + 2, WW) + c.tx;
    float gx3 = gcoord(w + 3, WW) + c.tx;
    int gi = idx * 3;
    out_g4[gi + 0] = (f4){gx0, gy, gz, gx1};
    out_g4[gi + 1] = (f4){gy, gz, gx2, gy};
    out_g4[gi + 2] = (f4){gz, gx3, gy, gz};

    // ---- trilinear: constant integer shift, 4 rows x 5 taps shared by 4 voxels
    int zi0 = d + c.dz0, zi1 = zi0 + 1;
    int yi0 = h + c.dy0, yi1 = yi0 + 1;
    int zs0 = min(max(zi0, 0), DD - 1), zs1 = min(max(zi1, 0), DD - 1);
    int ys0 = min(max(yi0, 0), HH - 1), ys1 = min(max(yi1, 0), HH - 1);
    float vz0 = ((unsigned)zi0 < (unsigned)DD) ? 1.f : 0.f;
    float vz1 = ((unsigned)zi1 < (unsigned)DD) ? 1.f : 0.f;
    float vy0 = ((unsigned)yi0 < (unsigned)HH) ? 1.f : 0.f;
    float vy1 = ((unsigned)yi1 < (unsigned)HH) ? 1.f : 0.f;
    float m00 = vz0 * vy0, m01 = vz0 * vy1, m10 = vz1 * vy0, m11 = vz1 * vy1;
    float w0 = c.wgt[0] * m00, w1 = c.wgt[1] * m00;
    float w2 = c.wgt[2] * m01, w3 = c.wgt[3] * m01;
    float w4 = c.wgt[4] * m10, w5 = c.wgt[5] * m10;
    float w6 = c.wgt[6] * m11, w7 = c.wgt[7] * m11;
    int rb00 = (zs0 * HH + ys0) * WW;
    int rb01 = (zs0 * HH + ys1) * WW;
    int rb10 = (zs1 * HH + ys0) * WW;
    int rb11 = (zs1 * HH + ys1) * WW;

    int s = w + c.dx0;
    float r00[5], r01[5], r10[5], r11[5];
    #pragma unroll
    for (int j = 0; j < 5; ++j) {
        int t = s + j;
        int xc = min(max(t, 0), WW - 1);
        float vx = ((unsigned)t < (unsigned)WW) ? 1.f : 0.f;
        r00[j] = x[rb00 + xc] * vx;
        r01[j] = x[rb01 + xc] * vx;
        r10[j] = x[rb10 + xc] * vx;
        r11[j] = x[rb11 + xc] * vx;
    }
    f4 o;
    #pragma unroll
    for (int k = 0; k < 4; ++k) {
        float v = r00[k] * w0;
        v = fmaf(r00[k + 1], w1, v);
        v = fmaf(r01[k],     w2, v);
        v = fmaf(r01[k + 1], w3, v);
        v = fmaf(r10[k],     w4, v);
        v = fmaf(r10[k + 1], w5, v);
        v = fmaf(r11[k],     w6, v);
        v = fmaf(r11[k + 1], w7, v);
        o[k] = v;
    }
    __builtin_nontemporal_store(o, out_t4 + idx);   // streaming, never re-read
}

extern "C" void kernel_launch(void* const* d_in, const int* in_sizes, int n_in,
                              void* d_out, int out_size, void* d_ws, size_t ws_size,
                              hipStream_t stream) {
    const float* x = (const float*)d_in[0];
    const float* y = (const float*)d_in[1];
    float* out = (float*)d_out;
    f4* out_t4 = (f4*)out;                    // transformed: NVOX floats
    f4* out_g4 = (f4*)(out + NVOX);           // grid: NVOX*3 floats, 16B-aligned
    double* gsum = (double*)d_ws;             // 8 doubles
    unsigned int* counter = (unsigned int*)((char*)d_ws + 64);
    Consts* cs = (Consts*)((char*)d_ws + 128);
    hipMemsetAsync(d_ws, 0, 128, stream);     // zero gsum + counter each run
    reduce_kernel<<<RB, RT, 0, stream>>>(x, y, gsum, counter, cs);
    main_kernel<<<NV4 / 256, 256, 0, stream>>>(x, cs, out_t4, out_g4);
}

// Round 2
// 197.191 us; speedup vs baseline: 1.2472x; 1.2472x over previous
//
#include <hip/hip_runtime.h>
#include <math.h>

#define DD 192
#define HH 192
#define WW 192
#define NVOX (DD*HH*WW)        // 7077888
#define NV4  (NVOX/4)          // 1769472
#define RB   1024              // reduction blocks
#define RT   256               // reduction threads per block

typedef float f4 __attribute__((ext_vector_type(4)));

struct Consts {
    float tx, ty, tz;          // grid translation
    float wgt[8];              // corner weights, index = dz*4+dy*2+dx
    int   dx0, dy0, dz0;       // integer corner offsets (floor of shift)
};

__device__ __forceinline__ float gcoord(int i, int n) {
    return -1.0f + (float)i * (2.0f / (float)(n - 1));
}

// quantities: 0:sum_x 1:sum x*gx 2:sum x*gy 3:sum x*gz  4..7: same for y
__global__ void reduce_kernel(const float* __restrict__ x,
                              const float* __restrict__ y,
                              double* __restrict__ partials) {
    double acc[8] = {0,0,0,0,0,0,0,0};
    int tid = blockIdx.x * blockDim.x + threadIdx.x;
    const float4* x4 = (const float4*)x;
    const float4* y4 = (const float4*)y;
    for (int i = tid; i < NV4; i += RB * RT) {
        float4 xv = x4[i];
        float4 yv = y4[i];
        int base = i * 4;
        int w = base % WW;          // multiple of 4
        int rem = base / WW;
        int h = rem % HH;
        int d = rem / HH;
        float gy = gcoord(h, HH);
        float gz = gcoord(d, DD);
        float xs[4] = {xv.x, xv.y, xv.z, xv.w};
        float ys[4] = {yv.x, yv.y, yv.z, yv.w};
        // group-sum in fp32 (4 values, ~1ulp), widen once -> 8 f64 adds/iter
        float sx = 0.f, sy = 0.f, sxg = 0.f, syg = 0.f;
        #pragma unroll
        for (int k = 0; k < 4; ++k) {
            float gx = gcoord(w + k, WW);
            sx += xs[k]; sxg = fmaf(xs[k], gx, sxg);
            sy += ys[k]; syg = fmaf(ys[k], gx, syg);
        }
        acc[0] += (double)sx;
        acc[1] += (double)sxg;
        acc[2] += (double)(sx * gy);
        acc[3] += (double)(sx * gz);
        acc[4] += (double)sy;
        acc[5] += (double)syg;
        acc[6] += (double)(sy * gy);
        acc[7] += (double)(sy * gz);
    }
    #pragma unroll
    for (int q = 0; q < 8; ++q) {
        double v = acc[q];
        #pragma unroll
        for (int off = 32; off > 0; off >>= 1)
            v += __shfl_down(v, off, 64);
        acc[q] = v;
    }
    __shared__ double lds[4][8];
    int lane = threadIdx.x & 63;
    int wave = threadIdx.x >> 6;
    if (lane == 0) {
        #pragma unroll
        for (int q = 0; q < 8; ++q) lds[wave][q] = acc[q];
    }
    __syncthreads();
    // plain per-block stores; kernel boundary provides the ordering
    if (threadIdx.x < 8) {
        int q = threadIdx.x;
        partials[q * RB + blockIdx.x] = lds[0][q] + lds[1][q] + lds[2][q] + lds[3][q];
    }
}

__global__ void finalize_kernel(const double* __restrict__ partials,
                                Consts* __restrict__ cs) {
    double s[8];
    #pragma unroll
    for (int q = 0; q < 8; ++q) {
        double v = 0.0;
        for (int i = threadIdx.x; i < RB; i += 256) v += partials[q * RB + i];
        #pragma unroll
        for (int off = 32; off > 0; off >>= 1)
            v += __shfl_down(v, off, 64);
        s[q] = v;
    }
    __shared__ double lds[4][8];
    int lane = threadIdx.x & 63;
    int wave = threadIdx.x >> 6;
    if (lane == 0) {
        #pragma unroll
        for (int q = 0; q < 8; ++q) lds[wave][q] = s[q];
    }
    __syncthreads();
    if (threadIdx.x == 0) {
        double sums[8];
        #pragma unroll
        for (int q = 0; q < 8; ++q)
            sums[q] = lds[0][q] + lds[1][q] + lds[2][q] + lds[3][q];
        double tx = sums[1] / sums[0] - sums[5] / sums[4];
        double ty = sums[2] / sums[0] - sums[6] / sums[4];
        double tz = sums[3] / sums[0] - sums[7] / sums[4];
        cs->tx = (float)tx; cs->ty = (float)ty; cs->tz = (float)tz;
        double cx = tx * (double)(WW - 1) * 0.5;
        double cy = ty * (double)(HH - 1) * 0.5;
        double cz = tz * (double)(DD - 1) * 0.5;
        double fx = floor(cx), fy = floor(cy), fz = floor(cz);
        float wx = (float)(cx - fx), wy = (float)(cy - fy), wz = (float)(cz - fz);
        cs->dx0 = (int)fx; cs->dy0 = (int)fy; cs->dz0 = (int)fz;
        #pragma unroll
        for (int k = 0; k < 8; ++k) {
            float wzz = (k & 4) ? wz : 1.0f - wz;
            float wyy = (k & 2) ? wy : 1.0f - wy;
            float wxx = (k & 1) ? wx : 1.0f - wx;
            cs->wgt[k] = wzz * wyy * wxx;
        }
    }
}

// Fused: grid write (direct float4) + constant-shift trilinear, 4 voxels/thread.
__global__ void __launch_bounds__(256) main_kernel(const float* __restrict__ x,
                                                   const Consts* __restrict__ csp,
                                                   f4* __restrict__ out_t4,
                                                   f4* __restrict__ out_g4) {
    const Consts c = *csp;              // uniform -> scalar loads
    int idx = blockIdx.x * 256 + threadIdx.x;   // quad index, 0..NV4-1
    int wq  = idx % (WW / 4);
    int rem = idx / (WW / 4);
    int h = rem % HH;
    int d = rem / HH;
    int w = wq * 4;

    // ---- grid output: 12 floats = 3 float4 per thread, direct stores
    float gy  = gcoord(h, HH) + c.ty;
    float gz  = gcoord(d, DD) + c.tz;
    float gx0 = gcoord(w + 0, WW) + c.tx;
    float gx1 = gcoord(w + 1, WW) + c.tx;
    float gx2 = gcoord(w + 2, WW) + c.tx;
    float gx3 = gcoord(w + 3, WW) + c.tx;
    int gi = idx * 3;
    out_g4[gi + 0] = (f4){gx0, gy, gz, gx1};
    out_g4[gi + 1] = (f4){gy, gz, gx2, gy};
    out_g4[gi + 2] = (f4){gz, gx3, gy, gz};

    // ---- trilinear: constant integer shift, 4 rows x 5 taps shared by 4 voxels
    int zi0 = d + c.dz0, zi1 = zi0 + 1;
    int yi0 = h + c.dy0, yi1 = yi0 + 1;
    int zs0 = min(max(zi0, 0), DD - 1), zs1 = min(max(zi1, 0), DD - 1);
    int ys0 = min(max(yi0, 0), HH - 1), ys1 = min(max(yi1, 0), HH - 1);
    float vz0 = ((unsigned)zi0 < (unsigned)DD) ? 1.f : 0.f;
    float vz1 = ((unsigned)zi1 < (unsigned)DD) ? 1.f : 0.f;
    float vy0 = ((unsigned)yi0 < (unsigned)HH) ? 1.f : 0.f;
    float vy1 = ((unsigned)yi1 < (unsigned)HH) ? 1.f : 0.f;
    float m00 = vz0 * vy0, m01 = vz0 * vy1, m10 = vz1 * vy0, m11 = vz1 * vy1;
    float w0 = c.wgt[0] * m00, w1 = c.wgt[1] * m00;
    float w2 = c.wgt[2] * m01, w3 = c.wgt[3] * m01;
    float w4 = c.wgt[4] * m10, w5 = c.wgt[5] * m10;
    float w6 = c.wgt[6] * m11, w7 = c.wgt[7] * m11;
    int rb00 = (zs0 * HH + ys0) * WW;
    int rb01 = (zs0 * HH + ys1) * WW;
    int rb10 = (zs1 * HH + ys0) * WW;
    int rb11 = (zs1 * HH + ys1) * WW;

    int s = w + c.dx0;
    float r00[5], r01[5], r10[5], r11[5];
    #pragma unroll
    for (int j = 0; j < 5; ++j) {
        int t = s + j;
        int xc = min(max(t, 0), WW - 1);
        float vx = ((unsigned)t < (unsigned)WW) ? 1.f : 0.f;
        r00[j] = x[rb00 + xc] * vx;
        r01[j] = x[rb01 + xc] * vx;
        r10[j] = x[rb10 + xc] * vx;
        r11[j] = x[rb11 + xc] * vx;
    }
    f4 o;
    #pragma unroll
    for (int k = 0; k < 4; ++k) {
        float v = r00[k] * w0;
        v = fmaf(r00[k + 1], w1, v);
        v = fmaf(r01[k],     w2, v);
        v = fmaf(r01[k + 1], w3, v);
        v = fmaf(r10[k],     w4, v);
        v = fmaf(r10[k + 1], w5, v);
        v = fmaf(r11[k],     w6, v);
        v = fmaf(r11[k + 1], w7, v);
        o[k] = v;
    }
    __builtin_nontemporal_store(o, out_t4 + idx);   // streaming, never re-read
}

extern "C" void kernel_launch(void* const* d_in, const int* in_sizes, int n_in,
                              void* d_out, int out_size, void* d_ws, size_t ws_size,
                              hipStream_t stream) {
    const float* x = (const float*)d_in[0];
    const float* y = (const float*)d_in[1];
    float* out = (float*)d_out;
    f4* out_t4 = (f4*)out;                    // transformed: NVOX floats
    f4* out_g4 = (f4*)(out + NVOX);           // grid: NVOX*3 floats, 16B-aligned
    double* partials = (double*)d_ws;         // 8*RB doubles = 64 KiB
    Consts* cs = (Consts*)((char*)d_ws + 8 * RB * sizeof(double));
    reduce_kernel<<<RB, RT, 0, stream>>>(x, y, partials);
    finalize_kernel<<<1, 256, 0, stream>>>(partials, cs);
    main_kernel<<<NV4 / 256, 256, 0, stream>>>(x, cs, out_t4, out_g4);
}

// Round 3
// 187.691 us; speedup vs baseline: 1.3104x; 1.0506x over previous
//
#include <hip/hip_runtime.h>
#include <math.h>

#define DD 192
#define HH 192
#define WW 192
#define NVOX (DD*HH*WW)        // 7077888
#define NV4  (NVOX/4)          // 1769472
#define RB   1024              // reduction blocks
#define RT   256               // reduction threads per block

typedef float f4 __attribute__((ext_vector_type(4)));

struct Consts {
    float tx, ty, tz;          // grid translation
    float wgt[8];              // corner weights, index = dz*4+dy*2+dx
    int   dx0, dy0, dz0;       // integer corner offsets (floor of shift)
};

__device__ __forceinline__ float gcoord(int i, int n) {
    return -1.0f + (float)i * (2.0f / (float)(n - 1));
}

// quantities: 0:sum_x 1:sum x*gx 2:sum x*gy 3:sum x*gz  4..7: same for y
__global__ void reduce_kernel(const float* __restrict__ x,
                              const float* __restrict__ y,
                              double* __restrict__ partials) {
    double acc[8] = {0,0,0,0,0,0,0,0};
    int tid = blockIdx.x * blockDim.x + threadIdx.x;
    const float4* x4 = (const float4*)x;
    const float4* y4 = (const float4*)y;
    for (int i = tid; i < NV4; i += RB * RT) {
        float4 xv = x4[i];
        float4 yv = y4[i];
        int base = i * 4;
        int w = base % WW;          // multiple of 4
        int rem = base / WW;
        int h = rem % HH;
        int d = rem / HH;
        float gy = gcoord(h, HH);
        float gz = gcoord(d, DD);
        float xs[4] = {xv.x, xv.y, xv.z, xv.w};
        float ys[4] = {yv.x, yv.y, yv.z, yv.w};
        // group-sum in fp32 (4 values, ~1ulp), widen once -> 8 f64 adds/iter
        float sx = 0.f, sy = 0.f, sxg = 0.f, syg = 0.f;
        #pragma unroll
        for (int k = 0; k < 4; ++k) {
            float gx = gcoord(w + k, WW);
            sx += xs[k]; sxg = fmaf(xs[k], gx, sxg);
            sy += ys[k]; syg = fmaf(ys[k], gx, syg);
        }
        acc[0] += (double)sx;
        acc[1] += (double)sxg;
        acc[2] += (double)(sx * gy);
        acc[3] += (double)(sx * gz);
        acc[4] += (double)sy;
        acc[5] += (double)syg;
        acc[6] += (double)(sy * gy);
        acc[7] += (double)(sy * gz);
    }
    #pragma unroll
    for (int q = 0; q < 8; ++q) {
        double v = acc[q];
        #pragma unroll
        for (int off = 32; off > 0; off >>= 1)
            v += __shfl_down(v, off, 64);
        acc[q] = v;
    }
    __shared__ double lds[4][8];
    int lane = threadIdx.x & 63;
    int wave = threadIdx.x >> 6;
    if (lane == 0) {
        #pragma unroll
        for (int q = 0; q < 8; ++q) lds[wave][q] = acc[q];
    }
    __syncthreads();
    // plain per-block stores; kernel boundary provides the ordering
    if (threadIdx.x < 8) {
        int q = threadIdx.x;
        partials[q * RB + blockIdx.x] = lds[0][q] + lds[1][q] + lds[2][q] + lds[3][q];
    }
}

__global__ void finalize_kernel(const double* __restrict__ partials,
                                Consts* __restrict__ cs) {
    double s[8];
    #pragma unroll
    for (int q = 0; q < 8; ++q) {
        double v = 0.0;
        for (int i = threadIdx.x; i < RB; i += 256) v += partials[q * RB + i];
        #pragma unroll
        for (int off = 32; off > 0; off >>= 1)
            v += __shfl_down(v, off, 64);
        s[q] = v;
    }
    __shared__ double lds[4][8];
    int lane = threadIdx.x & 63;
    int wave = threadIdx.x >> 6;
    if (lane == 0) {
        #pragma unroll
        for (int q = 0; q < 8; ++q) lds[wave][q] = s[q];
    }
    __syncthreads();
    if (threadIdx.x == 0) {
        double sums[8];
        #pragma unroll
        for (int q = 0; q < 8; ++q)
            sums[q] = lds[0][q] + lds[1][q] + lds[2][q] + lds[3][q];
        double tx = sums[1] / sums[0] - sums[5] / sums[4];
        double ty = sums[2] / sums[0] - sums[6] / sums[4];
        double tz = sums[3] / sums[0] - sums[7] / sums[4];
        cs->tx = (float)tx; cs->ty = (float)ty; cs->tz = (float)tz;
        double cx = tx * (double)(WW - 1) * 0.5;
        double cy = ty * (double)(HH - 1) * 0.5;
        double cz = tz * (double)(DD - 1) * 0.5;
        double fx = floor(cx), fy = floor(cy), fz = floor(cz);
        float wx = (float)(cx - fx), wy = (float)(cy - fy), wz = (float)(cz - fz);
        cs->dx0 = (int)fx; cs->dy0 = (int)fy; cs->dz0 = (int)fz;
        #pragma unroll
        for (int k = 0; k < 8; ++k) {
            float wzz = (k & 4) ? wz : 1.0f - wz;
            float wyy = (k & 2) ? wy : 1.0f - wy;
            float wxx = (k & 1) ? wx : 1.0f - wx;
            cs->wgt[k] = wzz * wyy * wxx;
        }
    }
}

// Fused: LDS-staged coalesced grid write + constant-shift trilinear, 4 vox/thread.
__global__ void __launch_bounds__(256) main_kernel(const float* __restrict__ x,
                                                   const Consts* __restrict__ csp,
                                                   f4* __restrict__ out_t4,
                                                   f4* __restrict__ out_g4) {
    __shared__ f4 gbuf[768];            // 1024 voxels * 3 comps = 3072 floats = 12 KB
    const Consts c = *csp;              // uniform -> scalar loads
    int t = threadIdx.x;
    int idx = blockIdx.x * 256 + t;     // quad index, 0..NV4-1
    int wq  = idx % (WW / 4);
    int rem = idx / (WW / 4);
    int h = rem % HH;
    int d = rem / HH;
    int w = wq * 4;

    // ---- trilinear setup: constant integer shift, issue loads early
    int zi0 = d + c.dz0, zi1 = zi0 + 1;
    int yi0 = h + c.dy0, yi1 = yi0 + 1;
    int zs0 = min(max(zi0, 0), DD - 1), zs1 = min(max(zi1, 0), DD - 1);
    int ys0 = min(max(yi0, 0), HH - 1), ys1 = min(max(yi1, 0), HH - 1);
    float vz0 = ((unsigned)zi0 < (unsigned)DD) ? 1.f : 0.f;
    float vz1 = ((unsigned)zi1 < (unsigned)DD) ? 1.f : 0.f;
    float vy0 = ((unsigned)yi0 < (unsigned)HH) ? 1.f : 0.f;
    float vy1 = ((unsigned)yi1 < (unsigned)HH) ? 1.f : 0.f;
    int rb00 = (zs0 * HH + ys0) * WW;
    int rb01 = (zs0 * HH + ys1) * WW;
    int rb10 = (zs1 * HH + ys0) * WW;
    int rb11 = (zs1 * HH + ys1) * WW;
    int s = w + c.dx0;
    float r00[5], r01[5], r10[5], r11[5];
    #pragma unroll
    for (int j = 0; j < 5; ++j) {
        int tt = s + j;
        int xc = min(max(tt, 0), WW - 1);
        float vx = ((unsigned)tt < (unsigned)WW) ? 1.f : 0.f;
        r00[j] = x[rb00 + xc] * vx;
        r01[j] = x[rb01 + xc] * vx;
        r10[j] = x[rb10 + xc] * vx;
        r11[j] = x[rb11 + xc] * vx;
    }

    // ---- grid: 12 floats/thread into LDS, then lane-contiguous f4 stores
    float gy  = gcoord(h, HH) + c.ty;
    float gz  = gcoord(d, DD) + c.tz;
    float gx0 = gcoord(w + 0, WW) + c.tx;
    float gx1 = gcoord(w + 1, WW) + c.tx;
    float gx2 = gcoord(w + 2, WW) + c.tx;
    float gx3 = gcoord(w + 3, WW) + c.tx;
    gbuf[3 * t + 0] = (f4){gx0, gy, gz, gx1};
    gbuf[3 * t + 1] = (f4){gy, gz, gx2, gy};
    gbuf[3 * t + 2] = (f4){gz, gx3, gy, gz};
    __syncthreads();
    f4* dst = out_g4 + (size_t)blockIdx.x * 768;
    dst[t]       = gbuf[t];
    dst[t + 256] = gbuf[t + 256];
    dst[t + 512] = gbuf[t + 512];

    // ---- stencil math + out store
    float m00 = vz0 * vy0, m01 = vz0 * vy1, m10 = vz1 * vy0, m11 = vz1 * vy1;
    float w0 = c.wgt[0] * m00, w1 = c.wgt[1] * m00;
    float w2 = c.wgt[2] * m01, w3 = c.wgt[3] * m01;
    float w4 = c.wgt[4] * m10, w5 = c.wgt[5] * m10;
    float w6 = c.wgt[6] * m11, w7 = c.wgt[7] * m11;
    f4 o;
    #pragma unroll
    for (int k = 0; k < 4; ++k) {
        float v = r00[k] * w0;
        v = fmaf(r00[k + 1], w1, v);
        v = fmaf(r01[k],     w2, v);
        v = fmaf(r01[k + 1], w3, v);
        v = fmaf(r10[k],     w4, v);
        v = fmaf(r10[k + 1], w5, v);
        v = fmaf(r11[k],     w6, v);
        v = fmaf(r11[k + 1], w7, v);
        o[k] = v;
    }
    out_t4[idx] = o;
}

extern "C" void kernel_launch(void* const* d_in, const int* in_sizes, int n_in,
                              void* d_out, int out_size, void* d_ws, size_t ws_size,
                              hipStream_t stream) {
    const float* x = (const float*)d_in[0];
    const float* y = (const float*)d_in[1];
    float* out = (float*)d_out;
    f4* out_t4 = (f4*)out;                    // transformed: NVOX floats
    f4* out_g4 = (f4*)(out + NVOX);           // grid: NVOX*3 floats, 16B-aligned
    double* partials = (double*)d_ws;         // 8*RB doubles = 64 KiB
    Consts* cs = (Consts*)((char*)d_ws + 8 * RB * sizeof(double));
    reduce_kernel<<<RB, RT, 0, stream>>>(x, y, partials);
    finalize_kernel<<<1, 256, 0, stream>>>(partials, cs);
    main_kernel<<<NV4 / 256, 256, 0, stream>>>(x, cs, out_t4, out_g4);
}

// Round 4
// 175.342 us; speedup vs baseline: 1.4027x; 1.0704x over previous
//
#include <hip/hip_runtime.h>
#include <math.h>

#define DD 192
#define HH 192
#define WW 192
#define NVOX (DD*HH*WW)        // 7077888
#define NV4  (NVOX/4)          // 1769472
#define RB   1024              // reduction blocks
#define RT   256               // reduction threads per block

struct Consts {
    float tx, ty, tz;          // grid translation
    float wgt[8];              // corner weights, index = dz*4+dy*2+dx
    int   dx0, dy0, dz0;       // integer corner offsets (floor of shift)
};

__device__ __forceinline__ float gcoord(int i, int n) {
    return -1.0f + (float)i * (2.0f / (float)(n - 1));
}

// quantities: 0:sum_x 1:sum x*gx 2:sum x*gy 3:sum x*gz  4..7: same for y
__global__ void reduce_kernel(const float* __restrict__ x,
                              const float* __restrict__ y,
                              double* __restrict__ partials) {
    double acc[8] = {0,0,0,0,0,0,0,0};
    int tid = blockIdx.x * blockDim.x + threadIdx.x;
    const float4* x4 = (const float4*)x;
    const float4* y4 = (const float4*)y;
    for (int i = tid; i < NV4; i += RB * RT) {
        float4 xv = x4[i];
        float4 yv = y4[i];
        int base = i * 4;
        int w = base % WW;          // multiple of 4
        int rem = base / WW;
        int h = rem % HH;
        int d = rem / HH;
        float gy = gcoord(h, HH);
        float gz = gcoord(d, DD);
        float xs[4] = {xv.x, xv.y, xv.z, xv.w};
        float ys[4] = {yv.x, yv.y, yv.z, yv.w};
        // group-sum in fp32 (4 values, ~1ulp), widen once -> 8 f64 adds/iter
        float sx = 0.f, sy = 0.f, sxg = 0.f, syg = 0.f;
        #pragma unroll
        for (int k = 0; k < 4; ++k) {
            float gx = gcoord(w + k, WW);
            sx += xs[k]; sxg = fmaf(xs[k], gx, sxg);
            sy += ys[k]; syg = fmaf(ys[k], gx, syg);
        }
        acc[0] += (double)sx;
        acc[1] += (double)sxg;
        acc[2] += (double)(sx * gy);
        acc[3] += (double)(sx * gz);
        acc[4] += (double)sy;
        acc[5] += (double)syg;
        acc[6] += (double)(sy * gy);
        acc[7] += (double)(sy * gz);
    }
    #pragma unroll
    for (int q = 0; q < 8; ++q) {
        double v = acc[q];
        #pragma unroll
        for (int off = 32; off > 0; off >>= 1)
            v += __shfl_down(v, off, 64);
        acc[q] = v;
    }
    __shared__ double lds[4][8];
    int lane = threadIdx.x & 63;
    int wave = threadIdx.x >> 6;
    if (lane == 0) {
        #pragma unroll
        for (int q = 0; q < 8; ++q) lds[wave][q] = acc[q];
    }
    __syncthreads();
    // plain per-block stores; kernel boundary provides the ordering
    if (threadIdx.x < 8) {
        int q = threadIdx.x;
        partials[q * RB + blockIdx.x] = lds[0][q] + lds[1][q] + lds[2][q] + lds[3][q];
    }
}

__global__ void finalize_kernel(const double* __restrict__ partials,
                                Consts* __restrict__ cs) {
    double s[8];
    #pragma unroll
    for (int q = 0; q < 8; ++q) {
        double v = 0.0;
        for (int i = threadIdx.x; i < RB; i += 256) v += partials[q * RB + i];
        #pragma unroll
        for (int off = 32; off > 0; off >>= 1)
            v += __shfl_down(v, off, 64);
        s[q] = v;
    }
    __shared__ double lds[4][8];
    int lane = threadIdx.x & 63;
    int wave = threadIdx.x >> 6;
    if (lane == 0) {
        #pragma unroll
        for (int q = 0; q < 8; ++q) lds[wave][q] = s[q];
    }
    __syncthreads();
    if (threadIdx.x == 0) {
        double sums[8];
        #pragma unroll
        for (int q = 0; q < 8; ++q)
            sums[q] = lds[0][q] + lds[1][q] + lds[2][q] + lds[3][q];
        double tx = sums[1] / sums[0] - sums[5] / sums[4];
        double ty = sums[2] / sums[0] - sums[6] / sums[4];
        double tz = sums[3] / sums[0] - sums[7] / sums[4];
        cs->tx = (float)tx; cs->ty = (float)ty; cs->tz = (float)tz;
        double cx = tx * (double)(WW - 1) * 0.5;
        double cy = ty * (double)(HH - 1) * 0.5;
        double cz = tz * (double)(DD - 1) * 0.5;
        double fx = floor(cx), fy = floor(cy), fz = floor(cz);
        float wx = (float)(cx - fx), wy = (float)(cy - fy), wz = (float)(cz - fz);
        cs->dx0 = (int)fx; cs->dy0 = (int)fy; cs->dz0 = (int)fz;
        #pragma unroll
        for (int k = 0; k < 8; ++k) {
            float wzz = (k & 4) ? wz : 1.0f - wz;
            float wyy = (k & 2) ? wy : 1.0f - wy;
            float wxx = (k & 1) ? wx : 1.0f - wx;
            cs->wgt[k] = wzz * wyy * wxx;
        }
    }
}

// Fused: grid write (LDS-staged, coalesced float4) + constant-shift trilinear stencil
// 1 voxel/thread: fully lane-contiguous x loads (4 B/lane), conflict-free LDS staging.
__global__ void __launch_bounds__(256) main_kernel(const float* __restrict__ x,
                                                   const Consts* __restrict__ csp,
                                                   float* __restrict__ out_t,
                                                   float4* __restrict__ out_g4) {
    __shared__ float gbuf[768];         // 256 voxels * 3 comps
    const Consts c = *csp;              // uniform address -> scalar loads
    int idx = blockIdx.x * 256 + threadIdx.x;
    int w = idx % WW;
    int rem = idx / WW;
    int h = rem % HH;
    int d = rem / HH;
    float gx = gcoord(w, WW) + c.tx;
    float gy = gcoord(h, HH) + c.ty;
    float gz = gcoord(d, DD) + c.tz;
    gbuf[3 * threadIdx.x + 0] = gx;
    gbuf[3 * threadIdx.x + 1] = gy;
    gbuf[3 * threadIdx.x + 2] = gz;
    __syncthreads();
    if (threadIdx.x < 192) {
        const float4* src = (const float4*)gbuf;
        out_g4[blockIdx.x * 192 + threadIdx.x] = src[threadIdx.x];
    }
    // trilinear: constant integer shift + constant weights, branchless validity
    int xi0 = w + c.dx0, yi0 = h + c.dy0, zi0 = d + c.dz0;
    int xi1 = xi0 + 1,  yi1 = yi0 + 1,  zi1 = zi0 + 1;
    int xs0 = min(max(xi0, 0), WW - 1), xs1 = min(max(xi1, 0), WW - 1);
    int ys0 = min(max(yi0, 0), HH - 1), ys1 = min(max(yi1, 0), HH - 1);
    int zs0 = min(max(zi0, 0), DD - 1), zs1 = min(max(zi1, 0), DD - 1);
    float vx0 = ((unsigned)xi0 < (unsigned)WW) ? 1.0f : 0.0f;
    float vx1 = ((unsigned)xi1 < (unsigned)WW) ? 1.0f : 0.0f;
    float vy0 = ((unsigned)yi0 < (unsigned)HH) ? 1.0f : 0.0f;
    float vy1 = ((unsigned)yi1 < (unsigned)HH) ? 1.0f : 0.0f;
    float vz0 = ((unsigned)zi0 < (unsigned)DD) ? 1.0f : 0.0f;
    float vz1 = ((unsigned)zi1 < (unsigned)DD) ? 1.0f : 0.0f;
    int rb00 = (zs0 * HH + ys0) * WW;
    int rb01 = (zs0 * HH + ys1) * WW;
    int rb10 = (zs1 * HH + ys0) * WW;
    int rb11 = (zs1 * HH + ys1) * WW;
    float acc =
        x[rb00 + xs0] * (c.wgt[0] * (vz0 * vy0 * vx0)) +
        x[rb00 + xs1] * (c.wgt[1] * (vz0 * vy0 * vx1)) +
        x[rb01 + xs0] * (c.wgt[2] * (vz0 * vy1 * vx0)) +
        x[rb01 + xs1] * (c.wgt[3] * (vz0 * vy1 * vx1)) +
        x[rb10 + xs0] * (c.wgt[4] * (vz1 * vy0 * vx0)) +
        x[rb10 + xs1] * (c.wgt[5] * (vz1 * vy0 * vx1)) +
        x[rb11 + xs0] * (c.wgt[6] * (vz1 * vy1 * vx0)) +
        x[rb11 + xs1] * (c.wgt[7] * (vz1 * vy1 * vx1));
    out_t[idx] = acc;
}

extern "C" void kernel_launch(void* const* d_in, const int* in_sizes, int n_in,
                              void* d_out, int out_size, void* d_ws, size_t ws_size,
                              hipStream_t stream) {
    const float* x = (const float*)d_in[0];
    const float* y = (const float*)d_in[1];
    float* out = (float*)d_out;
    float* out_t = out;                   // transformed: NVOX floats
    float4* out_g4 = (float4*)(out + NVOX); // grid: NVOX*3 floats, 16B-aligned
    double* partials = (double*)d_ws;     // 8*RB doubles = 64 KiB
    Consts* cs = (Consts*)((char*)d_ws + 8 * RB * sizeof(double));
    reduce_kernel<<<RB, RT, 0, stream>>>(x, y, partials);
    finalize_kernel<<<1, 256, 0, stream>>>(partials, cs);
    main_kernel<<<NVOX / 256, 256, 0, stream>>>(x, cs, out_t, out_g4);
}